// Round 7
// baseline (1274.095 us; speedup 1.0000x reference)
//
#include <hip/hip_runtime.h>

// DecoderLSTM R16: R15 (64 peds/block, 128 blocks, 3x32KB half-slab ring)
// with the ring-wrap race fixed. R15 bug: ring slot rb = H%3 with 20 halves
// per step (20%3!=0) -> at the wrap, ISSUE_HALF(0) targeted rb0 while half18
// still lived there; out-of-order DMA arrival corrupted weights (absmax .137).
// Fix: rolling rb counter with invariant "issue into the buffer just
// consumed" (advances 0->1->2->0; +2 phase per step). rb feeds addresses
// only (LDS offsets), never register-array indices.
// Design (unchanged from R15): halve chip-wide weight-stream demand by
// doubling peds/block -> 128 streaming CUs, 32 MFMA/half-stage,
// acc[4][4][2]; counted vmcnt(8), 4 loads/half/wave, wave-private chunks;
// __syncthreads everywhere. LDS 144.5 KB.

typedef float  f32x4  __attribute__((ext_vector_type(4)));
typedef short  short8 __attribute__((ext_vector_type(8)));
typedef __bf16 bf16x8 __attribute__((ext_vector_type(8)));

#define WS_W     0                      // 640 KB bf16 B-frags
#define WS_BIAS  (640 * 1024)           // 4 KB
#define WS_SCAL  (WS_BIAS + 4096)       // 64 B

__device__ __forceinline__ unsigned short f2bf(float f) {
  unsigned int u = __float_as_uint(f);
  u += 0x7FFFu + ((u >> 16) & 1u);  // RNE
  return (unsigned short)(u >> 16);
}
__device__ __forceinline__ float sigm(float x) {
  return __builtin_amdgcn_rcpf(1.0f + __expf(-x));
}
__device__ __forceinline__ float tanh_(float x) {
  float ax = fabsf(x);
  float t = __expf(-2.0f * ax);
  float r = (1.0f - t) * __builtin_amdgcn_rcpf(1.0f + t);
  return x >= 0.0f ? r : -r;
}
__device__ __forceinline__ f32x4 mfma16(short8 a, short8 b, f32x4 c) {
  return __builtin_amdgcn_mfma_f32_16x16x32_bf16(
      __builtin_bit_cast(bf16x8, a), __builtin_bit_cast(bf16x8, b), c, 0, 0, 0);
}

// ---- Prologue 1: weights -> B-frag bf16 ------------------------------------
// flat short idx = (kc*64 + nt)*512 + l*8 + j
// element: row(N=1024) = nt*16 + (l&15), col(K) = kc*32 + (l>>4)*8 + j
// nt = g*16 + w*2 + j  (wave w owns units w*32..w*32+31 of each gate)
extern "C" __global__ void shuffle_weights(const float* __restrict__ Wih,
                                           const float* __restrict__ Whh,
                                           unsigned short* __restrict__ ws_w) {
  int t = blockIdx.x * 256 + threadIdx.x;  // 0..40959
  if (t >= 40960) return;
  int l = t & 63;
  int nt = (t >> 6) & 63;
  int kc = t >> 12;  // 0..9
  int row = nt * 16 + (l & 15);
  int cb = (l >> 4) * 8;
  unsigned short* dst = ws_w + (size_t)t * 8;
  const float* src = (kc < 2) ? (Wih + row * 64 + kc * 32 + cb)
                              : (Whh + row * 256 + (kc - 2) * 32 + cb);
#pragma unroll
  for (int j = 0; j < 8; j++) dst[j] = f2bf(src[j]);
}

// ---- Prologue 2: bias + scal ------------------------------------------------
extern "C" __global__ void prologue2(const float* __restrict__ b_ih,
                                     const float* __restrict__ b_hh,
                                     const float* __restrict__ ln2g,
                                     const float* __restrict__ ln2b,
                                     const float* __restrict__ posW,
                                     float* __restrict__ biasv,
                                     float* __restrict__ scal) {
  int t = threadIdx.x;  // 256
#pragma unroll
  for (int k2 = 0; k2 < 4; k2++) {
    int n = t * 4 + k2;
    biasv[n] = b_ih[n] + b_hh[n];
  }
  __shared__ float red[256][4];
  float g = ln2g[t], b = ln2b[t], p0 = posW[t], p1 = posW[256 + t];
  red[t][0] = b * p0;
  red[t][1] = b * p1;
  red[t][2] = g * p0;
  red[t][3] = g * p1;
  __syncthreads();
  for (int s = 128; s > 0; s >>= 1) {
    if (t < s) {
#pragma unroll
      for (int v = 0; v < 4; v++) red[t][v] += red[t + s][v];
    }
    __syncthreads();
  }
  if (t == 0) {
#pragma unroll
    for (int v = 0; v < 4; v++) scal[v] = red[0][v];
  }
}

// Issue DMA for half-slab H (= kc*2 + hh) into ring buffer rbv:
// 4 x 1KB wave-private chunks (gg,j). LDS dest wave-uniform; src per-lane.
#define ISSUE_HALF(H, rbv)                                                   \
  {                                                                          \
    const int kc_ = (H) >> 1, hh_ = (H) & 1;                                 \
    _Pragma("unroll") for (int gg_ = 0; gg_ < 2; gg_++)                      \
        _Pragma("unroll") for (int j_ = 0; j_ < 2; j_++)                     \
            __builtin_amdgcn_global_load_lds(                                \
                (const unsigned int*)(ws_w + kc_ * 32768 +                   \
                                      (hh_ * 2 + gg_) * 8192 + w * 1024 +    \
                                      j_ * 512 + loff),                      \
                (unsigned int*)(wbuf + (rbv)*16384 + w * 2048 + gg_ * 1024 + \
                                j_ * 512),                                   \
                16, 0, 0);                                                   \
  }

// Consume half H from ring slot rb: wait its 4 loads (3 halves = 12 loads
// in flight -> vmcnt(8) retires the oldest 4), ds_read 4 B-frags, 16 MFMAs,
// then refill THIS buffer with half H+3 and advance rb. The 3 outstanding
// halves always occupy 3 distinct buffers (issue-into-consumed invariant).
#define HALF(H)                                                              \
  {                                                                          \
    asm volatile("s_waitcnt vmcnt(8)" ::: "memory");                         \
    const int hh_ = (H) & 1;                                                 \
    const unsigned short* lb_ = wbuf + rb * 16384 + w * 2048 + loff;         \
    short8 b00 = *(const short8*)(lb_);                                      \
    short8 b01 = *(const short8*)(lb_ + 512);                                \
    short8 b10 = *(const short8*)(lb_ + 1024);                               \
    short8 b11 = *(const short8*)(lb_ + 1536);                               \
    _Pragma("unroll") for (int mt_ = 0; mt_ < 4; mt_++) {                    \
      acc[mt_][hh_ * 2 + 0][0] = mfma16(a[mt_], b00, acc[mt_][hh_ * 2][0]);  \
      acc[mt_][hh_ * 2 + 0][1] = mfma16(a[mt_], b01, acc[mt_][hh_ * 2][1]);  \
      acc[mt_][hh_ * 2 + 1][0] =                                             \
          mfma16(a[mt_], b10, acc[mt_][hh_ * 2 + 1][0]);                     \
      acc[mt_][hh_ * 2 + 1][1] =                                             \
          mfma16(a[mt_], b11, acc[mt_][hh_ * 2 + 1][1]);                     \
    }                                                                        \
    asm volatile("s_waitcnt lgkmcnt(0)" ::: "memory");                       \
    ISSUE_HALF(((H) + 3) % 20, rb);                                          \
    rb = (rb == 2) ? 0 : rb + 1;                                             \
  }

#define STAGE_X(kc)                                                          \
  {                                                                          \
    short8 a[4];                                                             \
    _Pragma("unroll") for (int mt_ = 0; mt_ < 4; mt_++)                      \
        a[mt_] = *(const short8*)(xh + (mt_ * 2 + (kc)) * 512 + loff);       \
    HALF(2 * (kc));                                                          \
    HALF(2 * (kc) + 1);                                                      \
  }
#define STAGE_H(kh)                                                          \
  {                                                                          \
    short8 a[4];                                                             \
    _Pragma("unroll") for (int mt_ = 0; mt_ < 4; mt_++)                      \
        a[mt_] = *(const short8*)(h_stage + (mt_ * 8 + (kh)) * 512 + loff);  \
    HALF(2 * ((kh) + 2));                                                    \
    HALF(2 * ((kh) + 2) + 1);                                                \
  }

// ---- Main persistent decoder ------------------------------------------------
extern "C" __global__ __launch_bounds__(512, 1) void decoder_main(
    const float* __restrict__ lpr, const float* __restrict__ h0,
    const float* __restrict__ c0, const float* __restrict__ embW,
    const float* __restrict__ embB, const float* __restrict__ ln1g,
    const float* __restrict__ ln1b, const float* __restrict__ posW,
    const float* __restrict__ posB, const float* __restrict__ ln2g,
    const unsigned short* __restrict__ ws_w,
    const float* __restrict__ biasv, const float* __restrict__ scal,
    float* __restrict__ out) {
  __shared__ unsigned short wbuf[3 * 16384];    // 96 KB half-slab ring
  __shared__ unsigned short h_stage[32 * 512];  // 32 KB [mt*8+kc][l*8+j]
  __shared__ unsigned short xh[8 * 512];        // 8 KB  [mt*2+kc][l*8+j]
  __shared__ float partials[64 * 8 * 4];        // 8 KB  [ped][w] f32x4
  __shared__ float n01[64][2];                  // 512 B

  const int bid = blockIdx.x;
  const int tid = threadIdx.x;
  const int w = tid >> 6, l = tid & 63;
  const int q = l >> 4, li = l & 15;
  const int P0 = bid * 64;
  const int loff = l * 8;
  const int u0 = w * 32 + li;  // + j*16

  const float K0 = scal[0], K1 = scal[1], SP0 = scal[2], SP1 = scal[3];
  const float pb0 = posB[0], pb1 = posB[1];
  const float g10 = ln1g[0], g11 = ln1g[1], b10 = ln1b[0], b11 = ln1b[1];

  float bias_r[4][2];
#pragma unroll
  for (int g = 0; g < 4; g++)
#pragma unroll
    for (int j = 0; j < 2; j++) bias_r[g][j] = biasv[g * 256 + u0 + j * 16];
  float Pp0[2], Pp1[2];
#pragma unroll
  for (int j = 0; j < 2; j++) {
    float gg = ln2g[u0 + j * 16];
    Pp0[j] = gg * posW[u0 + j * 16];
    Pp1[j] = gg * posW[256 + u0 + j * 16];
  }

  // ---- c0 (64 peds: 4 m-tiles) ----
  f32x4 c_r[4][2];
#pragma unroll
  for (int mt = 0; mt < 4; mt++)
#pragma unroll
    for (int j = 0; j < 2; j++)
#pragma unroll
      for (int r = 0; r < 4; r++)
        c_r[mt][j][r] =
            c0[(size_t)(P0 + mt * 16 + q * 4 + r) * 256 + u0 + j * 16];

  // ---- h0 -> h_stage A-frags (64 peds x 256 units = 2048 short8 slots) ----
#pragma unroll
  for (int it = 0; it < 4; it++) {
    int f = tid + it * 512;        // 0..2047
    int ll = f & 63, fr = f >> 6;  // frag 0..31 = mt*8+kc
    int mt = fr >> 3, kc = fr & 7;
    const float* src = h0 + (size_t)(P0 + mt * 16 + (ll & 15)) * 256 +
                       kc * 32 + (ll >> 4) * 8;
    float4 ta = *(const float4*)(src);
    float4 tb = *(const float4*)(src + 4);
    short8 sv;
    sv[0] = (short)f2bf(ta.x); sv[1] = (short)f2bf(ta.y);
    sv[2] = (short)f2bf(ta.z); sv[3] = (short)f2bf(ta.w);
    sv[4] = (short)f2bf(tb.x); sv[5] = (short)f2bf(tb.y);
    sv[6] = (short)f2bf(tb.z); sv[7] = (short)f2bf(tb.w);
    *(short8*)(h_stage + f * 8) = sv;
  }

  // ---- n01 from lpr ----
  if (tid < 64) {
    float r0 = lpr[(P0 + tid) * 2], r1 = lpr[(P0 + tid) * 2 + 1];
    float d = 0.5f * (r0 - r1);
    float rs = rsqrtf(d * d + 1e-5f);
    n01[tid][0] = d * rs * g10 + b10;
    n01[tid][1] = -d * rs * g11 + b11;
  }
  __syncthreads();

  // ---- x0 = embed(n01) -> xh (8 threads/ped, 8 k each) ----
  {
    const int pc = tid >> 3, s8 = tid & 7;
    float n0 = n01[pc][0], n1 = n01[pc][1];
    int mt = pc >> 4, row = pc & 15;
#pragma unroll
    for (int jj = 0; jj < 8; jj++) {
      int k = s8 * 8 + jj;
      float e = n0 * embW[k * 2] + n1 * embW[k * 2 + 1] + embB[k];
      e = e > 0.f ? e : 0.01f * e;
      xh[(mt * 2 + (k >> 5)) * 512 + (row + 16 * ((k & 31) >> 3)) * 8 +
         (k & 7)] = f2bf(e);
    }
  }
  __syncthreads();

  // ---- prime the ring: halves 0,1,2 -> buffers 0,1,2 ----
  ISSUE_HALF(0, 0);
  ISSUE_HALF(1, 1);
  ISSUE_HALF(2, 2);
  int rb = 0;  // ring slot of the next half to consume

  for (int st = 0; st < 30; st++) {
    f32x4 acc[4][4][2];
#pragma unroll
    for (int mt = 0; mt < 4; mt++)
#pragma unroll
      for (int g = 0; g < 4; g++)
#pragma unroll
        for (int j = 0; j < 2; j++)
          acc[mt][g][j] = (f32x4){bias_r[g][j], bias_r[g][j], bias_r[g][j],
                                  bias_r[g][j]};

    // ---- 10 kc stages x 2 halves, weights via 3-buffer half-slab ring ----
    STAGE_X(0);
    STAGE_X(1);
    STAGE_H(0);
    STAGE_H(1);
    STAGE_H(2);
    STAGE_H(3);
    STAGE_H(4);
    STAGE_H(5);
    STAGE_H(6);
    STAGE_H(7);  // last halves re-issue 0,1,2 for the next step
    __syncthreads();  // A: all xh/h_stage reads done

    // ---- cell: c/h update, h -> h_stage A-frags, stats reduce ----
#pragma unroll
    for (int mt = 0; mt < 4; mt++) {
      float sh[4], sh2[4], sA[4], sB[4];
#pragma unroll
      for (int r = 0; r < 4; r++) {
        sh[r] = 0.f; sh2[r] = 0.f; sA[r] = 0.f; sB[r] = 0.f;
      }
#pragma unroll
      for (int j = 0; j < 2; j++) {
#pragma unroll
        for (int r = 0; r < 4; r++) {
          float iv = sigm(acc[mt][0][j][r]);
          float fv = sigm(acc[mt][1][j][r]);
          float gv = tanh_(acc[mt][2][j][r]);
          float ov = sigm(acc[mt][3][j][r]);
          float cc = fv * c_r[mt][j][r] + iv * gv;
          c_r[mt][j][r] = cc;
          float hv = ov * tanh_(cc);
          // unit u = w*32 + j*16 + li -> frag kc = w, col = j*16+li
          h_stage[(mt * 8 + w) * 512 +
                  ((q * 4 + r) + 16 * (j * 2 + (li >> 3))) * 8 + (li & 7)] =
              f2bf(hv);
          sh[r] += hv;
          sh2[r] += hv * hv;
          sA[r] += hv * Pp0[j];
          sB[r] += hv * Pp1[j];
        }
      }
#pragma unroll
      for (int mask = 1; mask <= 8; mask <<= 1) {
#pragma unroll
        for (int r = 0; r < 4; r++) {
          sh[r] += __shfl_xor(sh[r], mask, 64);
          sh2[r] += __shfl_xor(sh2[r], mask, 64);
          sA[r] += __shfl_xor(sA[r], mask, 64);
          sB[r] += __shfl_xor(sB[r], mask, 64);
        }
      }
      if (li == 0) {
#pragma unroll
        for (int r = 0; r < 4; r++)
          *(f32x4*)(partials + ((mt * 16 + q * 4 + r) * 8 + w) * 4) =
              (f32x4){sh[r], sh2[r], sA[r], sB[r]};
      }
    }
    __syncthreads();  // B: h_stage(t+1) + partials complete

    // ---- LN + rel + out + n01 (one thread per ped) ----
    if (tid < 64) {
      f32x4 sv = *(const f32x4*)(partials + tid * 32);
#pragma unroll
      for (int ww = 1; ww < 8; ww++) {
        f32x4 t2 = *(const f32x4*)(partials + (tid * 8 + ww) * 4);
        sv.x += t2.x; sv.y += t2.y; sv.z += t2.z; sv.w += t2.w;
      }
      float mu = sv.x * (1.0f / 256.0f);
      float var = sv.y * (1.0f / 256.0f) - mu * mu;
      float rsig = rsqrtf(var + 1e-5f);
      float rel0 = sigm(rsig * (sv.z - mu * SP0) + K0 + pb0);
      float rel1 = sigm(rsig * (sv.w - mu * SP1) + K1 + pb1);
      *(float2*)(out + (size_t)st * 16384 + (P0 + tid) * 2) =
          make_float2(rel0, rel1);
      float d = 0.5f * (rel0 - rel1);
      float rs = rsqrtf(d * d + 1e-5f);
      n01[tid][0] = d * rs * g10 + b10;
      n01[tid][1] = -d * rs * g11 + b11;
    }
    __syncthreads();  // C: n01 ready

    // ---- x_{t+1} = embed(rel) -> xh ----
    {
      const int pc = tid >> 3, s8 = tid & 7;
      float n0 = n01[pc][0], n1 = n01[pc][1];
      int mt = pc >> 4, row = pc & 15;
#pragma unroll
      for (int jj = 0; jj < 8; jj++) {
        int k = s8 * 8 + jj;
        float e = n0 * embW[k * 2] + n1 * embW[k * 2 + 1] + embB[k];
        e = e > 0.f ? e : 0.01f * e;
        xh[(mt * 2 + (k >> 5)) * 512 + (row + 16 * ((k & 31) >> 3)) * 8 +
           (k & 7)] = f2bf(e);
      }
    }
    __syncthreads();  // D: xh ready; drains vmcnt so counted waits restart
  }
}

extern "C" void kernel_launch(void* const* d_in, const int* in_sizes, int n_in,
                              void* d_out, int out_size, void* d_ws,
                              size_t ws_size, hipStream_t stream) {
  (void)in_sizes; (void)n_in; (void)out_size; (void)ws_size;
  const float* lpr  = (const float*)d_in[1];
  const float* h0   = (const float*)d_in[2];
  const float* c0   = (const float*)d_in[3];
  const float* Wih  = (const float*)d_in[4];
  const float* Whh  = (const float*)d_in[5];
  const float* b_ih = (const float*)d_in[6];
  const float* b_hh = (const float*)d_in[7];
  const float* embW = (const float*)d_in[8];
  const float* embB = (const float*)d_in[9];
  const float* ln1g = (const float*)d_in[10];
  const float* ln1b = (const float*)d_in[11];
  const float* posW = (const float*)d_in[12];
  const float* posB = (const float*)d_in[13];
  const float* ln2g = (const float*)d_in[14];
  const float* ln2b = (const float*)d_in[15];

  char* ws = (char*)d_ws;
  unsigned short* ws_w = (unsigned short*)(ws + WS_W);
  float* biasv  = (float*)(ws + WS_BIAS);
  float* scal   = (float*)(ws + WS_SCAL);

  shuffle_weights<<<dim3(160), dim3(256), 0, stream>>>(Wih, Whh, ws_w);
  prologue2<<<dim3(1), dim3(256), 0, stream>>>(b_ih, b_hh, ln2g, ln2b, posW,
                                               biasv, scal);
  decoder_main<<<dim3(128), dim3(512), 0, stream>>>(
      lpr, h0, c0, embW, embB, ln1g, ln1b, posW, posB, ln2g, ws_w, biasv,
      scal, (float*)d_out);
}

// Round 8
// 720.285 us; speedup vs baseline: 1.7689x; 1.7689x over previous
//
#include <hip/hip_runtime.h>

// DecoderLSTM R17: back to the R9 resident 2-block partition (488us round-0
// best); streaming (R13-R16: 716-1196us) is refuted — dur tracks an L2-miss
// path (~0.8TB/s) that no ordering/block-count change improved. R17 attacks
// R9's measured bottleneck: the rendezvous (~10 of 16.3us/step).
//   1. Tag protocol: sc-store h+stats -> drain -> barrier -> tag store;
//      readers spin on partner tag (no atomic RMW, one fewer barrier+spin).
//   2. Overlap: own-h MFMA (4 of 10 stages, partner-independent) runs BEFORE
//      the spin; rel_{t-1}/out/embed/x-MFMA/partner-h MFMA after.
//   3. Same-XCD pairing: partner = bid^8 (round-robin dispatch), pg/ug
//      remapped; barriers/step 7 -> 4-5.
// Cell math, layouts, weight shuffle, batched sc asm: verbatim R9.

typedef float  f32x4  __attribute__((ext_vector_type(4)));
typedef short  short8 __attribute__((ext_vector_type(8)));
typedef __bf16 bf16x8 __attribute__((ext_vector_type(8)));
typedef int    i32x4  __attribute__((ext_vector_type(4)));

#define WS_W     0                      // 640 KB (2 ug x 320 KB)
#define WS_HBUF  (640 * 1024)           // 8 MB: [2][128pg][2ug][16c][64] i32x4
#define WS_SBUF  (WS_HBUF + 8388608)    // 512 KB: [2][128][2][64] i32x4
#define WS_BIAS  (WS_SBUF + 524288)     // 4 KB
#define WS_SCAL  (WS_BIAS + 4096)       // 64 B
#define WS_CTR   (WS_SCAL + 64)         // 256 tag slots x 128 B

__device__ __forceinline__ unsigned short f2bf(float f) {
  unsigned int u = __float_as_uint(f);
  u += 0x7FFFu + ((u >> 16) & 1u);  // RNE
  return (unsigned short)(u >> 16);
}
__device__ __forceinline__ float sigm(float x) {
  return __builtin_amdgcn_rcpf(1.0f + __expf(-x));
}
__device__ __forceinline__ float tanh_(float x) {
  float ax = fabsf(x);
  float t = __expf(-2.0f * ax);
  float r = (1.0f - t) * __builtin_amdgcn_rcpf(1.0f + t);
  return x >= 0.0f ? r : -r;
}
__device__ __forceinline__ f32x4 mfma16(short8 a, short8 b, f32x4 c) {
  return __builtin_amdgcn_mfma_f32_16x16x32_bf16(
      __builtin_bit_cast(bf16x8, a), __builtin_bit_cast(bf16x8, b), c, 0, 0, 0);
}
__device__ __forceinline__ void sc_store16(void* p, i32x4 v) {
  asm volatile("global_store_dwordx4 %0, %1, off sc0 sc1" ::"v"(p), "v"(v)
               : "memory");
}
__device__ __forceinline__ void sc_load16(const i32x4* p, i32x4& r) {
  asm volatile(
      "global_load_dwordx4 %0, %1, off sc0 sc1\n\t"
      "s_waitcnt vmcnt(0)"
      : "=v"(r) : "v"(p) : "memory");
}
__device__ __forceinline__ void drain_vm() {
  asm volatile("s_waitcnt vmcnt(0)" ::: "memory");
}
// 3 coherent 16B loads, results valid at asm exit (waitcnt inside).
__device__ __forceinline__ void batch_load3(const i32x4* p0, const i32x4* p1,
                                            const i32x4* p2, i32x4& r0,
                                            i32x4& r1, i32x4& r2) {
  asm volatile(
      "global_load_dwordx4 %0, %3, off sc0 sc1\n\t"
      "global_load_dwordx4 %1, %4, off sc0 sc1\n\t"
      "global_load_dwordx4 %2, %5, off sc0 sc1\n\t"
      "s_waitcnt vmcnt(0)"
      : "=&v"(r0), "=&v"(r1), "=&v"(r2)
      : "v"(p0), "v"(p1), "v"(p2)
      : "memory");
}

// ---- Prologue 1: weights -> B-frag bf16 (verbatim R9) ----------------------
// flat idx: (((ug*10 + kc)*8 + w)*4 + g)*512 + l*8 + j
extern "C" __global__ void shuffle_weights(const float* __restrict__ Wih,
                                           const float* __restrict__ Whh,
                                           unsigned short* __restrict__ ws_w) {
  int t = blockIdx.x * 256 + threadIdx.x;  // 0..40959
  if (t >= 40960) return;
  int l = t & 63;
  int g = (t >> 6) & 3;
  int w8 = (t >> 8) & 7;
  int y = t >> 11;  // ug*10 + kc
  int kc = y % 10;
  int ug = y / 10;
  int row = g * 256 + ug * 128 + w8 * 16 + (l & 15);
  unsigned short* dst = ws_w + (size_t)t * 8;
  if (kc < 2) {
    const float* src = Wih + row * 64 + kc * 32 + (l >> 4) * 8;
#pragma unroll
    for (int j = 0; j < 8; j++) dst[j] = f2bf(src[j]);
  } else {
    const float* src = Whh + row * 256 + (kc - 2) * 32 + (l >> 4) * 8;
#pragma unroll
    for (int j = 0; j < 8; j++) dst[j] = f2bf(src[j]);
  }
}

// ---- Prologue 2: bias, scal, zero 256 tag slots -----------------------------
extern "C" __global__ void prologue2(const float* __restrict__ b_ih,
                                     const float* __restrict__ b_hh,
                                     const float* __restrict__ ln2g,
                                     const float* __restrict__ ln2b,
                                     const float* __restrict__ posW,
                                     float* __restrict__ biasv,
                                     float* __restrict__ scal,
                                     int* __restrict__ ctr) {
  int t = threadIdx.x;  // 256
#pragma unroll
  for (int k2 = 0; k2 < 4; k2++) {
    int n = t * 4 + k2;
    biasv[n] = b_ih[n] + b_hh[n];
  }
  ctr[t * 32] = 0;  // tag slot (pg*2+ug)*32, 128B apart
  __shared__ float red[256][4];
  float g = ln2g[t], b = ln2b[t], p0 = posW[t], p1 = posW[256 + t];
  red[t][0] = b * p0;
  red[t][1] = b * p1;
  red[t][2] = g * p0;
  red[t][3] = g * p1;
  __syncthreads();
  for (int s = 128; s > 0; s >>= 1) {
    if (t < s) {
#pragma unroll
      for (int v = 0; v < 4; v++) red[t][v] += red[t + s][v];
    }
    __syncthreads();
  }
  if (t == 0) {
#pragma unroll
    for (int v = 0; v < 4; v++) scal[v] = red[0][v];
  }
}

// one MFMA stage: 4 A-frags x 4 gates (BGET may use g_)
#define MF_STAGE(A0, A1, A2, A3, BGET)                                     \
  {                                                                        \
    short8 a0_ = (A0), a1_ = (A1), a2_ = (A2), a3_ = (A3);                 \
    _Pragma("unroll") for (int g_ = 0; g_ < 4; g_++) {                     \
      short8 b_ = (BGET);                                                  \
      acc[g_][0] = mfma16(a0_, b_, acc[g_][0]);                            \
      acc[g_][1] = mfma16(a1_, b_, acc[g_][1]);                            \
      acc[g_][2] = mfma16(a2_, b_, acc[g_][2]);                            \
      acc[g_][3] = mfma16(a3_, b_, acc[g_][3]);                            \
    }                                                                      \
  }
#define HSA(kh, mt) (*(const short8*)(h_stage + ((mt)*8 + (kh)) * 512 + loff))
#define XA(k2, mt)  (*(const short8*)(xh + ((mt)*2 + (k2)) * 512 + loff))
#define WL(kc, g)   (*(const short8*)(w_lds + (((kc)*8 + w) * 4 + (g)) * 512 + loff))

// ---- Main persistent decoder ------------------------------------------------
extern "C" __global__ __launch_bounds__(512, 2) void decoder_main(
    const float* __restrict__ lpr, const float* __restrict__ h0,
    const float* __restrict__ c0, const float* __restrict__ embW,
    const float* __restrict__ embB, const float* __restrict__ ln1g,
    const float* __restrict__ ln1b, const float* __restrict__ posW,
    const float* __restrict__ posB, const float* __restrict__ ln2g,
    const unsigned short* __restrict__ ws_w,
    unsigned short* __restrict__ hbuf,  // h exchange
    float* __restrict__ sbuf,           // stats exchange
    const float* __restrict__ biasv, const float* __restrict__ scal,
    int* __restrict__ ctr, float* __restrict__ out) {
  __shared__ unsigned short w_lds[3 * 8 * 4 * 512];  // 96 KB, kc 0..2
  __shared__ unsigned short h_stage[4 * 8 * 512];    // 32 KB [mt][kh][512]
  __shared__ unsigned short xh[4 * 2 * 512];         // 8 KB x A-frags
  __shared__ float partials[64 * 8 * 4];             // 8 KB [ped][w] f32x4
  __shared__ float n01[64][2];                       // 512 B

  const int bid = blockIdx.x;
  // same-XCD pairing: blocks bid and bid^8 share XCD under round-robin
  const int ug = (bid >> 3) & 1;
  const int pg = (bid & 7) | ((bid >> 4) << 3);  // 0..127
  const int tid = threadIdx.x;
  const int w = tid >> 6, l = tid & 63;
  const int q = l >> 4, li = l & 15;
  const int P0 = pg * 64;
  const int loff = l * 8;
  const int u = ug * 128 + w * 16 + li;

  // ---- weights: LDS part (kc 0..2) ----
  {
    const unsigned short* src = ws_w + (size_t)ug * 163840;
#pragma unroll
    for (int it = 0; it < 12; it++) {
      int f = tid + it * 512;
      *(short8*)(w_lds + f * 8) = *(const short8*)(src + f * 8);
    }
  }
  // ---- weights: register part (kc 3..9) ----
  short8 wr[7][4];
#pragma unroll
  for (int kk = 0; kk < 7; kk++)
#pragma unroll
    for (int g = 0; g < 4; g++)
      wr[kk][g] = *(const short8*)(ws_w + (size_t)ug * 163840 +
                                   (((kk + 3) * 8 + w) * 4 + g) * 512 + loff);

  const float K0 = scal[0], K1 = scal[1], SP0 = scal[2], SP1 = scal[3];
  const float pb0 = posB[0], pb1 = posB[1];
  const float g10 = ln1g[0], g11 = ln1g[1], b10 = ln1b[0], b11 = ln1b[1];

  float bias_r[4];
#pragma unroll
  for (int g = 0; g < 4; g++) bias_r[g] = biasv[g * 256 + u];
  float Pp0, Pp1;
  {
    float gg = ln2g[u];
    Pp0 = gg * posW[u];
    Pp1 = gg * posW[256 + u];
  }

  // ---- c0 ----
  f32x4 c_r[4];
#pragma unroll
  for (int mt = 0; mt < 4; mt++)
#pragma unroll
    for (int r = 0; r < 4; r++)
      c_r[mt][r] = c0[(size_t)(P0 + mt * 16 + q * 4 + r) * 256 + u];

  // ---- h0 -> h_stage (full 256 units for 64 peds) ----
#pragma unroll
  for (int it = 0; it < 4; it++) {
    int f = tid + it * 512;  // 0..2047 short8-slots
    int ll = f & 63, kc = (f >> 6) & 7, Tl = f >> 9;
    const float* src =
        h0 + (size_t)(P0 + Tl * 16 + (ll & 15)) * 256 + kc * 32 + (ll >> 4) * 8;
    float4 ta = *(const float4*)(src);
    float4 tb = *(const float4*)(src + 4);
    short8 sv;
    sv[0] = (short)f2bf(ta.x); sv[1] = (short)f2bf(ta.y);
    sv[2] = (short)f2bf(ta.z); sv[3] = (short)f2bf(ta.w);
    sv[4] = (short)f2bf(tb.x); sv[5] = (short)f2bf(tb.y);
    sv[6] = (short)f2bf(tb.z); sv[7] = (short)f2bf(tb.w);
    *(short8*)(h_stage + f * 8) = sv;
  }

  // ---- n01 from lpr ----
  if (tid < 64) {
    float r0 = lpr[(P0 + tid) * 2], r1 = lpr[(P0 + tid) * 2 + 1];
    float d = 0.5f * (r0 - r1);
    float rs = rsqrtf(d * d + 1e-5f);
    n01[tid][0] = d * rs * g10 + b10;
    n01[tid][1] = -d * rs * g11 + b11;
  }
  __syncthreads();

  // ---- x0 = embed(n01) into xh (8 threads/ped, 8 k each) ----
  {
    const int pc = tid >> 3, s8 = tid & 7;
    float n0 = n01[pc][0], n1 = n01[pc][1];
    int Tl = pc >> 4, row = pc & 15;
#pragma unroll
    for (int jj = 0; jj < 8; jj++) {
      int k = s8 * 8 + jj;
      float e = n0 * embW[k * 2] + n1 * embW[k * 2 + 1] + embB[k];
      e = e > 0.f ? e : 0.01f * e;
      xh[(Tl * 2 + (k >> 5)) * 512 + (row + 16 * ((k & 31) >> 3)) * 8 + (k & 7)] =
          f2bf(e);
    }
  }
  __syncthreads();

  i32x4* hb4 = (i32x4*)hbuf;
  i32x4* sb4 = (i32x4*)sbuf;
  i32x4* hs4 = (i32x4*)h_stage;
  const size_t own_base = ((size_t)pg * 2 + ug) * 1024;
  const size_t par_base = ((size_t)pg * 2 + (ug ^ 1)) * 1024;
  const size_t sown_base = ((size_t)pg * 2 + ug) * 64;
  const size_t spar_base = ((size_t)pg * 2 + (ug ^ 1)) * 64;
  int* tag_own = ctr + (pg * 2 + ug) * 32;
  int* tag_par = ctr + (pg * 2 + (ug ^ 1)) * 32;
  f32x4 sown = (f32x4){0.f, 0.f, 0.f, 0.f};

  for (int st = 0; st < 30; st++) {
    f32x4 acc[4][4];
#pragma unroll
    for (int g = 0; g < 4; g++)
#pragma unroll
      for (int mt = 0; mt < 4; mt++)
        acc[g][mt] = (f32x4){bias_r[g], bias_r[g], bias_r[g], bias_r[g]};

    // ---- phase 0: OWN-h MFMA (partner-independent; overlaps flight) ----
    if (ug == 0) {
      MF_STAGE(HSA(0, 0), HSA(0, 1), HSA(0, 2), HSA(0, 3), WL(2, g_));
      MF_STAGE(HSA(1, 0), HSA(1, 1), HSA(1, 2), HSA(1, 3), wr[0][g_]);
      MF_STAGE(HSA(2, 0), HSA(2, 1), HSA(2, 2), HSA(2, 3), wr[1][g_]);
      MF_STAGE(HSA(3, 0), HSA(3, 1), HSA(3, 2), HSA(3, 3), wr[2][g_]);
    } else {
      MF_STAGE(HSA(4, 0), HSA(4, 1), HSA(4, 2), HSA(4, 3), wr[3][g_]);
      MF_STAGE(HSA(5, 0), HSA(5, 1), HSA(5, 2), HSA(5, 3), wr[4][g_]);
      MF_STAGE(HSA(6, 0), HSA(6, 1), HSA(6, 2), HSA(6, 3), wr[5][g_]);
      MF_STAGE(HSA(7, 0), HSA(7, 1), HSA(7, 2), HSA(7, 3), wr[6][g_]);
    }

    // ---- phase 1: rendezvous (consume partner h_st + stats_{st-1}) ----
    if (st > 0) {
      while (__hip_atomic_load(tag_par, __ATOMIC_RELAXED,
                               __HIP_MEMORY_SCOPE_AGENT) < st)
        __builtin_amdgcn_s_sleep(1);
      const size_t pbase = (size_t)((st - 1) & 1) * 262144;
      const size_t sbase = (size_t)((st - 1) & 1) * 16384;
      const i32x4* p0 = hb4 + pbase + par_base + tid;
      const i32x4* p1 = p0 + 512;
      const i32x4* p2 = (tid < 64) ? (sb4 + sbase + spar_base + tid) : p0;
      i32x4 r0, r1, r2;
      batch_load3(p0, p1, p2, r0, r1, r2);
      {
        int c0i = tid >> 6, rr = tid & 63;
        hs4[((c0i >> 2) * 8 + (ug ^ 1) * 4 + (c0i & 3)) * 64 + rr] = r0;
        int f1 = tid + 512;
        int c1 = f1 >> 6, rr1 = f1 & 63;
        hs4[((c1 >> 2) * 8 + (ug ^ 1) * 4 + (c1 & 3)) * 64 + rr1] = r1;
      }
      if (tid < 64) {
        f32x4 sp = __builtin_bit_cast(f32x4, r2);
        float S = sown.x + sp.x;
        float S2 = sown.y + sp.y;
        float D0 = sown.z + sp.z;
        float D1 = sown.w + sp.w;
        float mu = S * (1.0f / 256.0f);
        float var = S2 * (1.0f / 256.0f) - mu * mu;
        float rsig = rsqrtf(var + 1e-5f);
        float rel0 = sigm(rsig * (D0 - mu * SP0) + K0 + pb0);
        float rel1 = sigm(rsig * (D1 - mu * SP1) + K1 + pb1);
        if (ug == 0)
          *(float2*)(out + (size_t)(st - 1) * 16384 + (P0 + tid) * 2) =
              make_float2(rel0, rel1);
        float d = 0.5f * (rel0 - rel1);
        float rs = rsqrtf(d * d + 1e-5f);
        n01[tid][0] = d * rs * g10 + b10;
        n01[tid][1] = -d * rs * g11 + b11;
      }
      __syncthreads();  // #1: partner slots + n01 visible
      {
        const int pc = tid >> 3, s8 = tid & 7;
        float n0 = n01[pc][0], n1 = n01[pc][1];
        int Tl = pc >> 4, row = pc & 15;
#pragma unroll
        for (int jj = 0; jj < 8; jj++) {
          int k = s8 * 8 + jj;
          float e = n0 * embW[k * 2] + n1 * embW[k * 2 + 1] + embB[k];
          e = e > 0.f ? e : 0.01f * e;
          xh[(Tl * 2 + (k >> 5)) * 512 + (row + 16 * ((k & 31) >> 3)) * 8 +
             (k & 7)] = f2bf(e);
        }
      }
      __syncthreads();  // #2: xh visible
    }

    // ---- phase 2: x MFMA + partner-h MFMA ----
    MF_STAGE(XA(0, 0), XA(0, 1), XA(0, 2), XA(0, 3), WL(0, g_));
    MF_STAGE(XA(1, 0), XA(1, 1), XA(1, 2), XA(1, 3), WL(1, g_));
    if (ug == 0) {
      MF_STAGE(HSA(4, 0), HSA(4, 1), HSA(4, 2), HSA(4, 3), wr[3][g_]);
      MF_STAGE(HSA(5, 0), HSA(5, 1), HSA(5, 2), HSA(5, 3), wr[4][g_]);
      MF_STAGE(HSA(6, 0), HSA(6, 1), HSA(6, 2), HSA(6, 3), wr[5][g_]);
      MF_STAGE(HSA(7, 0), HSA(7, 1), HSA(7, 2), HSA(7, 3), wr[6][g_]);
    } else {
      MF_STAGE(HSA(0, 0), HSA(0, 1), HSA(0, 2), HSA(0, 3), WL(2, g_));
      MF_STAGE(HSA(1, 0), HSA(1, 1), HSA(1, 2), HSA(1, 3), wr[0][g_]);
      MF_STAGE(HSA(2, 0), HSA(2, 1), HSA(2, 2), HSA(2, 3), wr[1][g_]);
      MF_STAGE(HSA(3, 0), HSA(3, 1), HSA(3, 2), HSA(3, 3), wr[2][g_]);
    }
    if (st == 0) __syncthreads();  // st>0: barriers #1/#2 already separate
                                   // phase-0 own-slot reads from cell writes

    // ---- cell: c/h update, own h -> h_stage own slots, stats (verbatim) ----
#pragma unroll
    for (int mt = 0; mt < 4; mt++) {
      float sh[4], sh2[4], sA[4], sB[4];
#pragma unroll
      for (int r = 0; r < 4; r++) {
        float iv = sigm(acc[0][mt][r]);
        float fv = sigm(acc[1][mt][r]);
        float gv = tanh_(acc[2][mt][r]);
        float ov = sigm(acc[3][mt][r]);
        float cc = fv * c_r[mt][r] + iv * gv;
        c_r[mt][r] = cc;
        float hv = ov * tanh_(cc);
        // own unit u_loc = w*16+li -> kh = ug*4 + (w>>1), ksub = (w&1)*16+li
        h_stage[(mt * 8 + ug * 4 + (w >> 1)) * 512 +
                ((q * 4 + r) + 16 * ((w & 1) * 2 + (li >> 3))) * 8 + (li & 7)] =
            f2bf(hv);
        sh[r] = hv;
        sh2[r] = hv * hv;
        sA[r] = hv * Pp0;
        sB[r] = hv * Pp1;
      }
#pragma unroll
      for (int mask = 1; mask <= 8; mask <<= 1) {
#pragma unroll
        for (int r = 0; r < 4; r++) {
          sh[r] += __shfl_xor(sh[r], mask, 64);
          sh2[r] += __shfl_xor(sh2[r], mask, 64);
          sA[r] += __shfl_xor(sA[r], mask, 64);
          sB[r] += __shfl_xor(sB[r], mask, 64);
        }
      }
      if (li == 0) {
#pragma unroll
        for (int r = 0; r < 4; r++)
          *(f32x4*)(partials + ((mt * 16 + q * 4 + r) * 8 + w) * 4) =
              (f32x4){sh[r], sh2[r], sA[r], sB[r]};
      }
    }
    __syncthreads();  // B: own h in h_stage + partials complete

    // ---- post: own h sc-store + stats combine/sc-store; drain; tag ----
    {
      const size_t pbase_w = (size_t)(st & 1) * 262144;
      const size_t sbase_w = (size_t)(st & 1) * 16384;
      if (st < 29) {
#pragma unroll
        for (int it = 0; it < 2; it++) {
          int f = tid + it * 512;  // 0..1023
          int c = f >> 6, rr = f & 63;
          int mt = c >> 2, kcl = c & 3;
          i32x4 v = hs4[(mt * 8 + ug * 4 + kcl) * 64 + rr];
          sc_store16(hb4 + pbase_w + own_base + f, v);
        }
      }
      if (tid < 64) {
        f32x4 sv = *(const f32x4*)(partials + tid * 32);
#pragma unroll
        for (int ww = 1; ww < 8; ww++) {
          f32x4 t2 = *(const f32x4*)(partials + (tid * 8 + ww) * 4);
          sv.x += t2.x; sv.y += t2.y; sv.z += t2.z; sv.w += t2.w;
        }
        sown = sv;
        sc_store16(sb4 + sbase_w + sown_base + tid,
                   __builtin_bit_cast(i32x4, sv));
      }
      drain_vm();
      __syncthreads();  // E: all waves' sc-stores drained
      if (tid == 0)
        __hip_atomic_store(tag_own, st + 1, __ATOMIC_RELAXED,
                           __HIP_MEMORY_SCOPE_AGENT);
    }
  }

  // ---- epilogue: rel_29 from stats posted at iter 29 (parity 1) ----
  while (__hip_atomic_load(tag_par, __ATOMIC_RELAXED,
                           __HIP_MEMORY_SCOPE_AGENT) < 30)
    __builtin_amdgcn_s_sleep(1);
  if (tid < 64) {
    i32x4 r2;
    sc_load16(sb4 + 16384 + spar_base + tid, r2);
    f32x4 sp = __builtin_bit_cast(f32x4, r2);
    float S = sown.x + sp.x;
    float S2 = sown.y + sp.y;
    float D0 = sown.z + sp.z;
    float D1 = sown.w + sp.w;
    float mu = S * (1.0f / 256.0f);
    float var = S2 * (1.0f / 256.0f) - mu * mu;
    float rsig = rsqrtf(var + 1e-5f);
    float rel0 = sigm(rsig * (D0 - mu * SP0) + K0 + pb0);
    float rel1 = sigm(rsig * (D1 - mu * SP1) + K1 + pb1);
    if (ug == 0)
      *(float2*)(out + (size_t)29 * 16384 + (P0 + tid) * 2) =
          make_float2(rel0, rel1);
  }
}

extern "C" void kernel_launch(void* const* d_in, const int* in_sizes, int n_in,
                              void* d_out, int out_size, void* d_ws,
                              size_t ws_size, hipStream_t stream) {
  (void)in_sizes; (void)n_in; (void)out_size; (void)ws_size;
  const float* lpr  = (const float*)d_in[1];
  const float* h0   = (const float*)d_in[2];
  const float* c0   = (const float*)d_in[3];
  const float* Wih  = (const float*)d_in[4];
  const float* Whh  = (const float*)d_in[5];
  const float* b_ih = (const float*)d_in[6];
  const float* b_hh = (const float*)d_in[7];
  const float* embW = (const float*)d_in[8];
  const float* embB = (const float*)d_in[9];
  const float* ln1g = (const float*)d_in[10];
  const float* ln1b = (const float*)d_in[11];
  const float* posW = (const float*)d_in[12];
  const float* posB = (const float*)d_in[13];
  const float* ln2g = (const float*)d_in[14];
  const float* ln2b = (const float*)d_in[15];

  char* ws = (char*)d_ws;
  unsigned short* ws_w = (unsigned short*)(ws + WS_W);
  unsigned short* hbuf = (unsigned short*)(ws + WS_HBUF);
  float* sbufp  = (float*)(ws + WS_SBUF);
  float* biasv  = (float*)(ws + WS_BIAS);
  float* scal   = (float*)(ws + WS_SCAL);
  int*   ctr    = (int*)(ws + WS_CTR);

  shuffle_weights<<<dim3(160), dim3(256), 0, stream>>>(Wih, Whh, ws_w);
  prologue2<<<dim3(1), dim3(256), 0, stream>>>(b_ih, b_hh, ln2g, ln2b, posW,
                                               biasv, scal, ctr);
  decoder_main<<<dim3(256), dim3(512), 0, stream>>>(
      lpr, h0, c0, embW, embB, ln1g, ln1b, posW, posB, ln2g, ws_w, hbuf,
      sbufp, biasv, scal, ctr, (float*)d_out);
}